// Round 14
// baseline (58.842 us; speedup 1.0000x reference)
//
#include <hip/hip_runtime.h>

typedef _Float16 f16;
typedef _Float16 f16x8 __attribute__((ext_vector_type(8)));
typedef _Float16 f16x4 __attribute__((ext_vector_type(4)));
typedef float    f32x4 __attribute__((ext_vector_type(4)));
typedef int      i32x4 __attribute__((ext_vector_type(4)));

#define MFMA16(a,b,c) __builtin_amdgcn_mfma_f32_16x16x32_f16((a),(b),(c),0,0,0)
#define MFMAI8(a,b,c) __builtin_amdgcn_mfma_i32_16x16x64_i8((a),(b),(c),0,0,0)
#define AS1(p) ((const __attribute__((address_space(1))) void*)(p))
#define AS3(p) ((__attribute__((address_space(3))) void*)(p))

constexpr int   NH   = 12;
constexpr int   SEQ  = 1024;
constexpr float INV128 = 1.0f/128.0f;
constexpr int   ECAP = 98304;
constexpr float THR_NOT = -4.5948f;   // ln(1/0.99 - 1) rounded toward safe side

__device__ __forceinline__ float q8f(float x){ return rintf(x*128.0f)*INV128; }
__device__ __forceinline__ float q4f(float x){ return rintf(x*8.0f)*0.125f; }

// ---------------- K0: merged prelude ----------------
__global__ __launch_bounds__(256) void prelude(
    const float* __restrict__ x, const float* __restrict__ qkv_w,
    float* __restrict__ out, const float* __restrict__ pb,
    const float* __restrict__ biases, int NU,
    f16* __restrict__ xq, f16* __restrict__ wqk,
    float* __restrict__ Bh, int* __restrict__ cnt2)
{
    const int b = blockIdx.x, t = threadIdx.x;
    if (b < 6144){
        int i = (b*256 + t)*4;
        float4 v = *(const float4*)(x + i);
        f16x4 o;
        o[0]=(f16)q8f(v.x); o[1]=(f16)q8f(v.y); o[2]=(f16)q8f(v.z); o[3]=(f16)q8f(v.w);
        *(f16x4*)(xq + i) = o;
    } else if (b < 7296){
        int i = ((b-6144)*256 + t)*4;        // element in wqk [1536][768]
        int r = i / 768, col = i - r*768;
        int srow = (r>>7)*384 + (r&127);
        float4 v = *(const float4*)(qkv_w + (size_t)srow*768 + col);
        f16x4 o;
        o[0]=(f16)q8f(v.x); o[1]=(f16)q8f(v.y); o[2]=(f16)q8f(v.z); o[3]=(f16)q8f(v.w);
        *(f16x4*)(wqk + i) = o;
    } else if (b < 13440){
        int i = ((b-7296)*256 + t)*4;
        int c = i % 768;
        float4 v = { pb[c], pb[c+1], pb[c+2], pb[c+3] };
        *(float4*)(out + i) = v;
    } else {
        int h = b - 13440;
        float m = 0.f;
        for (int i = t; i < NU; i += 256) m = fmaxf(m, fabsf(biases[h*NU + i]));
        #pragma unroll
        for (int d=32; d>=1; d>>=1) m = fmaxf(m, __shfl_xor(m, d));
        __shared__ float s[4];
        if ((t&63)==0) s[t>>6] = m;
        __syncthreads();
        if (t==0){
            Bh[h] = fmaxf(fmaxf(s[0],s[1]), fmaxf(s[2],s[3]));
            if (h==0) *cnt2 = 0;
        }
    }
}

// ---------------- K1: QK GEMM 8192x1536x768 — 128x192 tile, 4 waves, 2 blocks/CU ----
__global__ __launch_bounds__(256, 2) void gemm_qk(
    const f16* __restrict__ Aq, const f16* __restrict__ Wqk,
    const float* __restrict__ g, const float* __restrict__ bb,
    signed char* __restrict__ Qi, signed char* __restrict__ Ki)
{
    __shared__ f16 As[2][128][64];   // 32 KB
    __shared__ f16 Bs[2][192][64];   // 48 KB   (80 KB total -> 2 blocks/CU)
    const int t = threadIdx.x;
    const int bid = blockIdx.x;              // 0..511
    const int xcd = bid & 7, idx = bid >> 3;
    const int mt  = xcd*8 + (idx >> 3);      // 0..63
    const int nt  = idx & 7;                 // 0..7
    const int row0 = mt*128, col0 = nt*192;
    const int w = t>>6, lane = t&63;
    const int wr = (w>>1)*64, wc = (w&1)*96;
    const int lr = lane&15, lg = lane>>4;

    const int rloc  = lane>>3;
    const int sgran = (lane&7) ^ rloc;
    const f16* Abase = Aq  + (size_t)(row0 + w*32 + rloc)*768 + sgran*8;
    const f16* Bbase = Wqk + (size_t)(col0 + w*48 + rloc)*768 + sgran*8;

    f32x4 acc[4][6] = {};

#define STAGE(buf, kt) { \
    const int ko = (kt)*64; \
    __builtin_amdgcn_global_load_lds(AS1(Abase + (size_t) 0*768 + ko), AS3(&As[buf][w*32 +  0][0]), 16, 0, 0); \
    __builtin_amdgcn_global_load_lds(AS1(Abase + (size_t) 8*768 + ko), AS3(&As[buf][w*32 +  8][0]), 16, 0, 0); \
    __builtin_amdgcn_global_load_lds(AS1(Abase + (size_t)16*768 + ko), AS3(&As[buf][w*32 + 16][0]), 16, 0, 0); \
    __builtin_amdgcn_global_load_lds(AS1(Abase + (size_t)24*768 + ko), AS3(&As[buf][w*32 + 24][0]), 16, 0, 0); \
    __builtin_amdgcn_global_load_lds(AS1(Bbase + (size_t) 0*768 + ko), AS3(&Bs[buf][w*48 +  0][0]), 16, 0, 0); \
    __builtin_amdgcn_global_load_lds(AS1(Bbase + (size_t) 8*768 + ko), AS3(&Bs[buf][w*48 +  8][0]), 16, 0, 0); \
    __builtin_amdgcn_global_load_lds(AS1(Bbase + (size_t)16*768 + ko), AS3(&Bs[buf][w*48 + 16][0]), 16, 0, 0); \
    __builtin_amdgcn_global_load_lds(AS1(Bbase + (size_t)24*768 + ko), AS3(&Bs[buf][w*48 + 24][0]), 16, 0, 0); \
    __builtin_amdgcn_global_load_lds(AS1(Bbase + (size_t)32*768 + ko), AS3(&Bs[buf][w*48 + 32][0]), 16, 0, 0); \
    __builtin_amdgcn_global_load_lds(AS1(Bbase + (size_t)40*768 + ko), AS3(&Bs[buf][w*48 + 40][0]), 16, 0, 0); }

    STAGE(0, 0)

    for (int kt = 0; kt < 12; kt++){
        __builtin_amdgcn_s_barrier();             // WAR: all waves done reading buf[kt&1]
        if (kt < 11){
            STAGE((kt+1)&1, kt+1)
            asm volatile("s_waitcnt vmcnt(10)" ::: "memory");   // tile kt's 10 loads done
        } else {
            asm volatile("s_waitcnt vmcnt(0)" ::: "memory");
        }
        __builtin_amdgcn_s_barrier();             // tile kt visible to all waves

        const int bsel = kt & 1;
        #pragma unroll
        for (int kk=0; kk<2; kk++){
            const int slot = ((kk*4 + lg) ^ (lr&7))*8;
            f16x8 af[4], bf[6];
            #pragma unroll
            for (int i=0;i<4;i++)
                af[i] = *(const f16x8*)&As[bsel][wr + i*16 + lr][slot];
            #pragma unroll
            for (int j=0;j<6;j++)
                bf[j] = *(const f16x8*)&Bs[bsel][wc + j*16 + lr][slot];
            __builtin_amdgcn_s_setprio(1);
            #pragma unroll
            for (int i=0;i<4;i++)
                #pragma unroll
                for (int j=0;j<6;j++)
                    acc[i][j] = MFMA16(af[i], bf[j], acc[i][j]);
            __builtin_amdgcn_s_setprio(0);
        }
    }
#undef STAGE

    #pragma unroll
    for (int j=0;j<6;j++){
        int c = col0 + wc + j*16 + lr;         // 0..1535
        int head = c >> 7, rr = c & 127;
        int gcol = head*384 + rr;
        float gg = g[gcol], bv = bb[gcol];
        signed char* dst = (rr < 64) ? Qi : Ki;
        int dcol = rr & 63;
        #pragma unroll
        for (int i=0;i<4;i++){
            #pragma unroll
            for (int r=0;r<4;r++){
                int grow = row0 + wr + i*16 + lg*4 + r;
                float h = __fadd_rn(__fmul_rn(acc[i][j][r], gg), bv);
                int iv = (int)rintf(q8f(h)*8.0f);     // q4 value x8: exact int8
                int bq = grow >> 10, n = grow & 1023;
                dst[((size_t)(bq*NH + head)*SEQ + n)*64 + dcol] = (signed char)iv;
            }
        }
    }
}

// ---------------- K2: pass A v2 — barrier-free global-streaming screen ----
// 384 blocks x 4 waves; each wave owns 64 q rows, streams all 1024 K rows
// directly from global (L2-resident), tracks max/second-max in registers.
__global__ __launch_bounds__(256) void pass_a(
    const signed char* __restrict__ Qi, const signed char* __restrict__ Ki,
    const float* __restrict__ Bh,
    int* __restrict__ cnt2, int2* __restrict__ amb)
{
    const int t = threadIdx.x;
    const int bid = blockIdx.x;                 // 0..383
    const int wg  = (bid & 7)*48 + (bid >> 3);  // XCD-chunk: 12 bh per XCD
    const int bh  = wg >> 2;
    const int qq  = wg & 3;                     // quarter of the q sequence
    const int lane = t&63, w = t>>6;
    const int n0 = qq*256 + w*64;               // this wave's 64 q rows
    const int lr = lane&15, lg = lane>>4;

    const float thr512 = (THR_NOT + 2.0f*Bh[bh % NH] + 1e-4f) * 512.0f;

    // A fragments: 4 x 16 q-rows, loaded once
    i32x4 aq[4];
    #pragma unroll
    for (int i=0;i<4;i++)
        aq[i] = *(const i32x4*)(Qi + ((size_t)bh*SEQ + n0 + i*16 + lr)*64 + lg*16);

    // K stream: lane reads row (kb+lr), bytes [lg*16, lg*16+16) -> wave covers
    // rows kb..kb+15 x 64B = 1 KB contiguous (coalesced)
    const signed char* kp = Ki + (size_t)bh*SEQ*64 + lr*64 + lg*16;

    int mx[4][4], m2[4][4];
    #pragma unroll
    for (int i=0;i<4;i++)
        #pragma unroll
        for (int r=0;r<4;r++){ mx[i][r] = -(1<<30); m2[i][r] = -(1<<30); }

    i32x4 kbuf = *(const i32x4*)(kp);
    #pragma unroll 4
    for (int kb = 0; kb < 1024; kb += 16){
        i32x4 knext;
        if (kb < 1008) knext = *(const i32x4*)(kp + (size_t)(kb+16)*64);
        #pragma unroll
        for (int i=0;i<4;i++){
            i32x4 c = {0,0,0,0};
            c = MFMAI8(aq[i], kbuf, c);
            #pragma unroll
            for (int r=0;r<4;r++){
                int sc = c[r];
                int om = mx[i][r];
                asm("v_med3_i32 %0, %1, %2, %3" : "=v"(m2[i][r]) : "v"(sc), "v"(m2[i][r]), "v"(om));
                mx[i][r] = max(om, sc);
            }
        }
        kbuf = knext;
    }

    #pragma unroll
    for (int i=0;i<4;i++){
        #pragma unroll
        for (int r=0;r<4;r++){
            int mxv = mx[i][r], m2v = m2[i][r];
            #pragma unroll
            for (int d=1; d<16; d<<=1){
                int mo  = __shfl_xor(mxv, d);
                int m2o = __shfl_xor(m2v, d);
                int sec = max(min(mxv, mo), (mxv >= mo) ? m2v : m2o);
                mxv = max(mxv, mo);
                m2v = sec;
            }
            if (lr == 0){
                if ((float)(m2v - mxv) < thr512){
                    int n = n0 + i*16 + lg*4 + r;
                    int pos = atomicAdd(cnt2, 1);
                    if (pos < ECAP) amb[pos] = make_int2((bh<<10) | n, 0);
                }
            }
        }
    }
}

// ---------------- K3: merged tail — exact resolve + rare-path correction ----
__global__ __launch_bounds__(256) void tail_kernel(
    const signed char* __restrict__ Qi, const signed char* __restrict__ Ki,
    const float* __restrict__ biases, int NU,
    const f16* __restrict__ xq, const f16* __restrict__ wqk,
    const float* __restrict__ qkv_w,
    const float* __restrict__ g, const float* __restrict__ bb,
    const float* __restrict__ proj_w, const float* __restrict__ pg,
    const int* __restrict__ cnt2, const int2* __restrict__ amb,
    float* __restrict__ out)
{
    __shared__ int   qr[64];
    __shared__ float rmax[4], rsum[4];
    __shared__ int   rarg[4];
    __shared__ float xr_n[768], xr_m[768];
    __shared__ float qs[64], ks[64];
    __shared__ float hq[256];
    __shared__ float s_as;
    __shared__ int   s_ms, s_flag;
    int total = *cnt2; if (total > ECAP) total = ECAP;
    const int t = threadIdx.x;
    for (int e = blockIdx.x; e < total; e += gridDim.x){
        int2 a = amb[e];
        int bh = a.x>>10, n = a.x&1023;
        int h = bh % NH, b = bh / NH;
        __syncthreads();
        if (t < 64) qr[t] = (int)Qi[((size_t)bh*SEQ + n)*64 + t];
        __syncthreads();

        // ---- exact biased resolve (int dot, bit-identical to reference) ----
        int rn = n>>5, cnn = n&31;
        float lmax = -3e38f; int larg = 0; float lsc[4];
        #pragma unroll
        for (int j=0;j<4;j++){
            int m = t + j*256;
            const signed char* kp = &Ki[((size_t)bh*SEQ + m)*64];
            int d = 0;
            for (int u=0; u<64; u++) d += qr[u]*(int)kp[u];
            int idx = __builtin_abs(rn-(m>>5))*32 + __builtin_abs(cnn-(m&31));
            lsc[j] = (float)d*(1.0f/512.0f) + biases[h*NU + idx];
            if (lsc[j] > lmax){ lmax = lsc[j]; larg = m; }
        }
        #pragma unroll
        for (int dd=32; dd>=1; dd>>=1){
            float mo = __shfl_xor(lmax, dd);
            int   ao = __shfl_xor(larg, dd);
            if (mo > lmax){ lmax = mo; larg = ao; }
        }
        if ((t&63)==0){ rmax[t>>6] = lmax; rarg[t>>6] = larg; }
        __syncthreads();
        float MX = rmax[0]; int ARG = rarg[0];
        #pragma unroll
        for (int k=1;k<4;k++){ if (rmax[k] > MX){ MX = rmax[k]; ARG = rarg[k]; } }
        float ls = 0.f;
        #pragma unroll
        for (int j=0;j<4;j++) ls += expf(lsc[j]-MX);
        #pragma unroll
        for (int dd=32; dd>=1; dd>>=1) ls += __shfl_xor(ls, dd);
        if ((t&63)==0) rsum[t>>6] = ls;
        __syncthreads();
        if (t==0){
            float SUM = rsum[0]+rsum[1]+rsum[2]+rsum[3];
            s_flag = (1.0f/SUM > 0.99f);
            s_ms = ARG;
        }
        __syncthreads();
        if (!s_flag) continue;
        const int ms = s_ms;

        // ---- correction: recompute q,k,v at q8 precision ----
        for (int i=t; i<768; i+=256){
            xr_n[i] = (float)xq[((size_t)b*SEQ + n)*768 + i];
            xr_m[i] = (float)xq[((size_t)b*SEQ + ms)*768 + i];
        }
        __syncthreads();
        if (t < 128){
            int col = t & 63;
            int qkr  = h*128 + (t<64 ? col : 64+col);
            int gcol = h*384 + (t<64 ? col : 64+col);
            const f16* wr = &wqk[(size_t)qkr*768];
            const float* xr = (t<64) ? xr_n : xr_m;
            float acc = 0.f;
            for (int d=0; d<768; d++) acc = fmaf(xr[d], (float)wr[d], acc);
            float hv = __fadd_rn(__fmul_rn(acc, g[gcol]), bb[gcol]);
            float v = q8f(hv);
            if (t<64) qs[col] = v; else ks[col] = v;
        }
        __syncthreads();
        if (t < 64){
            float p = qs[t]*ks[t];
            #pragma unroll
            for (int d=32; d>=1; d>>=1) p += __shfl_xor(p, d);
            if (t == 0){
                int idx = __builtin_abs((n>>5)-(ms>>5))*32 + __builtin_abs((n&31)-(ms&31));
                float ss = __fadd_rn(__fmul_rn(p, 0.125f), biases[h*NU + idx]);
                float mx2 = fmaxf(ss, 0.f);
                float es = expf(ss-mx2), e0 = expf(-mx2);
                float Z = fmaf(1023.f, e0, es);
                s_as = q8f(es/Z);     // off-argmax weights quantize to exactly 0
            }
        }
        __syncthreads();
        {
            int gcol = h*384 + 128 + t;
            const float* wr = &qkv_w[(size_t)gcol*768];   // quantize V weights on the fly
            float acc = 0.f;
            for (int d=0; d<768; d++) acc = fmaf(xr_m[d], q8f(wr[d]), acc);
            float hv = __fadd_rn(__fmul_rn(acc, g[gcol]), bb[gcol]);
            float vq = q8f(hv);
            float o = __fmul_rn(s_as, vq);
            float c6 = fminf(fmaxf(o+3.f, 0.f), 6.f);
            hq[t] = q8f(__fdiv_rn(__fmul_rn(o, c6), 6.f));
        }
        __syncthreads();
        #pragma unroll
        for (int cc=0; cc<3; cc++){
            int c = t + cc*256;
            float s = 0.f;
            for (int d=0; d<256; d++)
                s = fmaf(hq[d], q8f(proj_w[(size_t)c*3072 + h*256 + d]), s);
            atomicAdd(&out[((size_t)b*SEQ + n)*768 + c], __fmul_rn(pg[c], s));
        }
    }
}

extern "C" void kernel_launch(void* const* d_in, const int* in_sizes, int n_in,
                              void* d_out, int out_size, void* d_ws, size_t ws_size,
                              hipStream_t stream)
{
    const float* x       = (const float*)d_in[0];
    const float* qkv_w   = (const float*)d_in[1];
    const float* qkv_g   = (const float*)d_in[2];
    const float* qkv_b   = (const float*)d_in[3];
    const float* proj_w  = (const float*)d_in[4];
    const float* proj_g  = (const float*)d_in[5];
    const float* proj_b  = (const float*)d_in[6];
    const float* biases  = (const float*)d_in[7];
    const int NU = in_sizes[7] / NH;   // 1024

    char* w = (char*)d_ws;
    f16* xq  = (f16*)w; w += (size_t)8192*768*2;
    f16* wqk = (f16*)w; w += (size_t)1536*768*2;
    signed char* Qi = (signed char*)w; w += (size_t)96*1024*64;
    signed char* Ki = (signed char*)w; w += (size_t)96*1024*64;
    int* cnt2= (int*)w;  w += 16;
    float* Bh = (float*)w; w += 64;
    int2* amb = (int2*)w; w += (size_t)ECAP*8;

    prelude<<<13452, 256, 0, stream>>>(x, qkv_w, (float*)d_out, proj_b, biases, NU,
                                       xq, wqk, Bh, cnt2);

    gemm_qk<<<512, 256, 0, stream>>>(xq, wqk, qkv_g, qkv_b, Qi, Ki);

    pass_a<<<384, 256, 0, stream>>>(Qi, Ki, Bh, cnt2, amb);

    tail_kernel<<<256, 256, 0, stream>>>(Qi, Ki, biases, NU, xq, wqk, qkv_w,
                                         qkv_g, qkv_b, proj_w, proj_g,
                                         cnt2, amb, (float*)d_out);
}